// Round 9
// baseline (1529.244 us; speedup 1.0000x reference)
//
#include <hip/hip_runtime.h>
#include <hip/hip_bf16.h>

// Problem constants
#define BB    8
#define NNODE 128
#define CIN   512
#define HH    8
#define DDIM  64
#define HD    512   // H*D

typedef float f32x4 __attribute__((ext_vector_type(4)));
typedef short bf16x8 __attribute__((ext_vector_type(8)));

#define AS1 __attribute__((address_space(1)))
#define AS3 __attribute__((address_space(3)))

static __device__ __forceinline__ unsigned short f2bf(float f) {
    unsigned int x = __float_as_uint(f);
    x = x + 0x7FFFu + ((x >> 16) & 1u);
    return (unsigned short)(x >> 16);
}
static __device__ __forceinline__ float bf2f(short u) {
    return __uint_as_float(((unsigned int)(unsigned short)u) << 16);
}
static __device__ __forceinline__ bf16x8 pack8(f32x4 a, f32x4 b) {
    bf16x8 r;
    r[0] = (short)f2bf(a[0]); r[1] = (short)f2bf(a[1]);
    r[2] = (short)f2bf(a[2]); r[3] = (short)f2bf(a[3]);
    r[4] = (short)f2bf(b[0]); r[5] = (short)f2bf(b[1]);
    r[6] = (short)f2bf(b[2]); r[7] = (short)f2bf(b[3]);
    return r;
}

// ---------------------------------------------------------------------------
// Kernel 1: tiled transpose+convert Wq/Wk/Wv [c][hd] f32 -> WT [m][hd][c] bf16
// ---------------------------------------------------------------------------
__global__ __launch_bounds__(256) void k_wt(
    const float* __restrict__ Wq, const float* __restrict__ Wk,
    const float* __restrict__ Wv,
    unsigned short* __restrict__ WT)
{
    __shared__ unsigned short tile[64][72];
    const int cb = blockIdx.x;
    const int hb = blockIdx.y;
    const int m  = blockIdx.z;          // 0=Wq,1=Wk,2=Wv
    const float* W = (m == 0) ? Wq : (m == 1) ? Wk : Wv;
    const int t = threadIdx.x;

#pragma unroll
    for (int it = 0; it < 4; ++it) {
        int row = it * 16 + (t >> 4);
        int col = (t & 15) * 4;
        f32x4 v = *reinterpret_cast<const f32x4*>(W + (size_t)(cb * 64 + row) * HD + hb * 64 + col);
        tile[row][col + 0] = f2bf(v[0]);
        tile[row][col + 1] = f2bf(v[1]);
        tile[row][col + 2] = f2bf(v[2]);
        tile[row][col + 3] = f2bf(v[3]);
    }
    __syncthreads();

#pragma unroll
    for (int it = 0; it < 4; ++it) {
        int hd = it * 16 + (t >> 4);
        int c  = (t & 15) * 4;
        unsigned long long pk =
            (unsigned long long)(unsigned short)tile[c + 0][hd] |
            ((unsigned long long)(unsigned short)tile[c + 1][hd] << 16) |
            ((unsigned long long)(unsigned short)tile[c + 2][hd] << 32) |
            ((unsigned long long)(unsigned short)tile[c + 3][hd] << 48);
        *reinterpret_cast<unsigned long long*>(
            &WT[((size_t)(m + 1) * HD + hb * 64 + hd) * CIN + cb * 64 + c]) = pk;
    }
}

// ---------------------------------------------------------------------------
// Kernel 2: QKV projections via bf16 MFMA (unchanged).
// ---------------------------------------------------------------------------
__global__ __launch_bounds__(256) void k_qkv(
    const float* __restrict__ hin,
    const unsigned short* __restrict__ WT,
    const float* __restrict__ bq, const float* __restrict__ bk, const float* __restrict__ bv,
    float* __restrict__ Qo, float* __restrict__ Ko, float* __restrict__ Vo)
{
    __shared__ unsigned short hs[64][520];
    const int rt = blockIdx.x;
    const int ct = blockIdx.y;
    const int m  = blockIdx.z;
    const int t  = threadIdx.x;
    const int w  = t >> 6;
    const int l  = t & 63;
    const int g  = l >> 4;
    const int c15 = l & 15;
    const float* bias = (m == 0) ? bq : (m == 1) ? bk : bv;
    float* Out = (m == 0) ? Qo : (m == 1) ? Ko : Vo;
    const unsigned short* Wm = WT + (size_t)(m + 1) * HD * CIN;
    const int rowbase = rt * 64;
    const int colbase = ct * 64;

#pragma unroll
    for (int q = 0; q < 32; ++q) {
        int f = q * 1024 + t * 4;
        int row = f >> 9;
        int c = f & 511;
        f32x4 hv = *reinterpret_cast<const f32x4*>(hin + (size_t)(rowbase + row) * CIN + c);
        unsigned long long pk =
            (unsigned long long)f2bf(hv[0]) |
            ((unsigned long long)f2bf(hv[1]) << 16) |
            ((unsigned long long)f2bf(hv[2]) << 32) |
            ((unsigned long long)f2bf(hv[3]) << 48);
        *reinterpret_cast<unsigned long long*>(&hs[row][c]) = pk;
    }
    __syncthreads();

    f32x4 acc[4];
#pragma unroll
    for (int nf = 0; nf < 4; ++nf) acc[nf] = (f32x4){0.f, 0.f, 0.f, 0.f};

#pragma unroll
    for (int kt = 0; kt < 16; ++kt) {
        bf16x8 afr = *reinterpret_cast<const bf16x8*>(&hs[w * 16 + c15][kt * 32 + g * 8]);
#pragma unroll
        for (int nf = 0; nf < 4; ++nf) {
            const unsigned short* wp = Wm + (size_t)(colbase + nf * 16 + c15) * CIN + kt * 32 + g * 8;
            bf16x8 bfr = *reinterpret_cast<const bf16x8*>(wp);
            acc[nf] = __builtin_amdgcn_mfma_f32_16x16x32_bf16(afr, bfr, acc[nf], 0, 0, 0);
        }
    }

    const float scale = (m == 1) ? 0.125f : 1.0f;
#pragma unroll
    for (int nf = 0; nf < 4; ++nf) {
        int col = colbase + nf * 16 + c15;
        float bv_ = bias[col];
#pragma unroll
        for (int r = 0; r < 4; ++r) {
            int row = rowbase + w * 16 + g * 4 + r;
            Out[(size_t)row * HD + col] = (acc[nf][r] + bv_) * scale;
        }
    }
}

// ---------------------------------------------------------------------------
// Kernel 1c: We -> WT3, A-fragment-linear: m = c (lane&15), k = d.
// WT3[(h*8+ct)*8 + mt*2+kt][l][i] = bf16(We[ct*64+mt*16+(l&15)][h*64+kt*32+(l>>4)*8+i])
// ---------------------------------------------------------------------------
__global__ __launch_bounds__(256) void k_wt3(
    const float* __restrict__ We, unsigned short* __restrict__ WT3)
{
    const int h  = blockIdx.x;          // 0..7
    const int ct = blockIdx.y;          // 0..7
    const int t  = threadIdx.x;
#pragma unroll
    for (int it = 0; it < 2; ++it) {
        int s  = it * 256 + t;          // (mt,kt,l): 4*2*64 = 512
        int mt = s >> 7, kt = (s >> 6) & 1, l = s & 63;
        int c  = ct * 64 + mt * 16 + (l & 15);
        int hd = h * 64 + kt * 32 + (l >> 4) * 8;
        const float* src = We + (size_t)c * HD + hd;
        f32x4 v0 = *reinterpret_cast<const f32x4*>(src);
        f32x4 v1 = *reinterpret_cast<const f32x4*>(src + 4);
        size_t off = (((size_t)(h * 8 + ct) * 4 + mt) * 2 + kt) * 512 + l * 8;
        *reinterpret_cast<bf16x8*>(&WT3[off]) = pack8(v0, v1);
    }
}

// ---------------------------------------------------------------------------
// Kernel 1d: K (scaled f32) -> K2, B-fragment-linear: n = j, k = d.
// K2[((b*8+h)*2+kt)*8+nt][l][i] = bf16(Kw[b, nt*16+(l&15), h*64+kt*32+(l>>4)*8+i])
// ---------------------------------------------------------------------------
__global__ __launch_bounds__(256) void k_k2(
    const float* __restrict__ Kw, unsigned short* __restrict__ K2)
{
    const int b = blockIdx.x;           // 0..7
    const int h = blockIdx.y;           // 0..7
    const int t = threadIdx.x;
#pragma unroll
    for (int it = 0; it < 4; ++it) {
        int s  = it * 256 + t;          // (kt,nt,l): 2*8*64 = 1024
        int kt = s >> 9, nt = (s >> 6) & 7, l = s & 63;
        int j  = nt * 16 + (l & 15);
        int hd = h * 64 + kt * 32 + (l >> 4) * 8;
        const float* src = Kw + ((size_t)b * NNODE + j) * HD + hd;
        f32x4 v0 = *reinterpret_cast<const f32x4*>(src);
        f32x4 v1 = *reinterpret_cast<const f32x4*>(src + 4);
        size_t off = (((size_t)(b * 8 + h) * 2 + kt) * 8 + nt) * 512 + l * 8;
        *reinterpret_cast<bf16x8*>(&K2[off]) = pack8(v0, v1);
    }
}

// ---------------------------------------------------------------------------
// Kernel 3 v9 = v8 body, register budget pinned via backend attributes:
// amdgpu_waves_per_eu(4,4) -> 512/4 = 128 VGPR budget (v8 needs ~105).
// block = (b,i), 1024 thr = 16 waves = (head, j-half); 8 phases of 64 c;
// e f32 via global_load_lds into 3 swizzled buffers; counted vmcnt.
// ---------------------------------------------------------------------------
__global__
__attribute__((amdgpu_flat_work_group_size(1024, 1024), amdgpu_waves_per_eu(4, 4)))
void k_main(
    const float* __restrict__ e, const float* __restrict__ k_RW,
    const unsigned short* __restrict__ WT3, const unsigned short* __restrict__ K2,
    const float* __restrict__ be, const float* __restrict__ Qw,
    const float* __restrict__ Vw, float* __restrict__ out)
{
    __shared__ float e_s[3 * 8192];     // 3 x 32 KB tiles, [j 0..127][granule-swizzled c]
    __shared__ float s_lds[8][128];
    __shared__ float po[8][64];
    __shared__ float pd[8];

    const int bx = blockIdx.x;
    const int bi = (bx & 7) * 128 + (bx >> 3);   // XCD swizzle (1024 % 8 == 0)
    const int b  = bi >> 7;
    const int t  = threadIdx.x;
    const int w  = t >> 6;              // wave 0..15
    const int h  = w >> 1;              // head
    const int jh = w & 1;               // j-half
    const int l  = t & 63;
    const int g  = l >> 4;
    const int c15 = l & 15;
    const int sw  = c15 & 7;            // read-side granule swizzle key

    const float* ebase = e + (size_t)bi * NNODE * CIN;

    // ---- B' = bf16(Q*K) for this (h, jh): 8 frags; bias term folds into sc ----
    float sc[4] = {0.f, 0.f, 0.f, 0.f};
    bf16x8 Bp[2][4];
#pragma unroll
    for (int kt = 0; kt < 2; ++kt) {
        const float* qp  = Qw + (size_t)bi * HD + h * 64 + kt * 32 + g * 8;
        const float* bp_ = be + h * 64 + kt * 32 + g * 8;
        f32x4 qa = *reinterpret_cast<const f32x4*>(qp);
        f32x4 qb = *reinterpret_cast<const f32x4*>(qp + 4);
        f32x4 ba = *reinterpret_cast<const f32x4*>(bp_);
        f32x4 bb = *reinterpret_cast<const f32x4*>(bp_ + 4);
#pragma unroll
        for (int nt = 0; nt < 4; ++nt) {
            bf16x8 kf = *reinterpret_cast<const bf16x8*>(
                K2 + (((size_t)(b * 8 + h) * 2 + kt) * 8 + jh * 4 + nt) * 512 + l * 8);
            bf16x8 bpv;
            float ab = 0.f;
#pragma unroll
            for (int i = 0; i < 4; ++i) {
                float p = bf2f(kf[i]) * qa[i];
                bpv[i] = (short)f2bf(p);
                ab = fmaf(ba[i], p, ab);
            }
#pragma unroll
            for (int i = 4; i < 8; ++i) {
                float p = bf2f(kf[i]) * qb[i - 4];
                bpv[i] = (short)f2bf(p);
                ab = fmaf(bb[i - 4], p, ab);
            }
            Bp[kt][nt] = bpv;
            sc[nt] += ab;
        }
    }
    asm volatile("s_waitcnt vmcnt(0)" ::: "memory");
    __builtin_amdgcn_sched_barrier(0);

    // ---- staging: wave w covers rows [w*8, w*8+8) of the 128x64 tile ----
    // instr q: rows w*8+q*4+g; linear LDS dest (base + lane*16);
    // source granule pre-swizzled: c-granule = c15 ^ (q*4+g)  (row&7 == q*4+g).
#define STAGE(TT) do {                                                          \
        _Pragma("unroll")                                                       \
        for (int q_ = 0; q_ < 2; ++q_) {                                        \
            const float* src_ = ebase + (size_t)(w * 8 + q_ * 4 + g) * CIN      \
                                + (TT) * 64 + ((c15 ^ (q_ * 4 + g)) << 2);      \
            __builtin_amdgcn_global_load_lds(                                   \
                (const AS1 unsigned int*)src_,                                  \
                (AS3 unsigned int*)((char*)&e_s[0] + ((TT) % 3) * 32768         \
                                    + (w * 2 + q_) * 1024),                     \
                16, 0, 0);                                                      \
        }                                                                       \
    } while (0)

#define LOADA(CT) do {                                                          \
        const unsigned short* ap_ = WT3 + (size_t)(h * 8 + (CT)) * 4096 + l * 8;\
        _Pragma("unroll")                                                       \
        for (int f_ = 0; f_ < 8; ++f_)                                          \
            wA[f_] = *reinterpret_cast<const bf16x8*>(ap_ + f_ * 512);          \
    } while (0)

    bf16x8 wA[8];

    STAGE(0);
    STAGE(1);
    __builtin_amdgcn_sched_barrier(0);

#define PHASE(CT) do {                                                          \
        LOADA(CT);                                                              \
        __builtin_amdgcn_sched_barrier(0);                                      \
        asm volatile("s_waitcnt vmcnt(8)" ::: "memory");  /* older S done */    \
        __builtin_amdgcn_sched_barrier(0);                                      \
        __builtin_amdgcn_s_barrier();                                           \
        __builtin_amdgcn_sched_barrier(0);                                      \
        if ((CT) < 6) { STAGE((CT) + 2); }                                      \
        __builtin_amdgcn_sched_barrier(0);                                      \
        if ((CT) < 6) { asm volatile("s_waitcnt vmcnt(2)" ::: "memory"); }      \
        else          { asm volatile("s_waitcnt vmcnt(0)" ::: "memory"); }      \
        __builtin_amdgcn_sched_barrier(0);                                      \
        const float* ebuf_ = e_s + ((CT) % 3) * 8192;                           \
        _Pragma("unroll")                                                       \
        for (int mt_ = 0; mt_ < 4; ++mt_) {                                     \
            _Pragma("unroll")                                                   \
            for (int nt_ = 0; nt_ < 4; ++nt_) {                                 \
                f32x4 D_ = (f32x4){0.f, 0.f, 0.f, 0.f};                         \
                D_ = __builtin_amdgcn_mfma_f32_16x16x32_bf16(                   \
                        wA[mt_ * 2 + 0], Bp[0][nt_], D_, 0, 0, 0);              \
                D_ = __builtin_amdgcn_mfma_f32_16x16x32_bf16(                   \
                        wA[mt_ * 2 + 1], Bp[1][nt_], D_, 0, 0, 0);              \
                f32x4 ev_ = *reinterpret_cast<const f32x4*>(                    \
                    ebuf_ + (jh * 64 + nt_ * 16 + c15) * 64                     \
                          + (((mt_ * 4 + g) ^ sw) << 2));                       \
                sc[nt_] += ev_[0] * D_[0] + ev_[1] * D_[1]                      \
                         + ev_[2] * D_[2] + ev_[3] * D_[3];                     \
            }                                                                   \
        }                                                                       \
    } while (0)

    PHASE(0);
    PHASE(1);
    PHASE(2);
    PHASE(3);
    PHASE(4);
    PHASE(5);
    PHASE(6);
    PHASE(7);
#undef PHASE
#undef LOADA
#undef STAGE

    // ---- finalize: reduce over g (c-rows), exp/clip, * k_RW ----
    const float* krw = k_RW + (size_t)bi * NNODE + jh * 64;
#pragma unroll
    for (int nt = 0; nt < 4; ++nt) {
        float s = sc[nt];
        s += __shfl_xor(s, 16);
        s += __shfl_xor(s, 32);
        float sv = __expf(fminf(fmaxf(s, -5.f), 5.f)) * krw[nt * 16 + c15];
        if (g == 0) s_lds[h][jh * 64 + nt * 16 + c15] = sv;
    }

    // ---- PV partials over own j-half ----
    const float* Vb = Vw + ((size_t)b * NNODE + jh * 64) * HD + h * 64 + l;
    float o = 0.f, den = 0.f;
#pragma unroll 4
    for (int jl = 0; jl < 64; ++jl) {
        float sv = s_lds[h][jh * 64 + jl];
        o = fmaf(sv, Vb[(size_t)jl * HD], o);
        den += sv;
    }
    if (jh == 1) {
        po[h][l] = o;
        if (l == 0) pd[h] = den;
    }
    __syncthreads();
    if (jh == 0) {
        o   += po[h][l];
        den += pd[h];
        out[(size_t)bi * HD + h * 64 + l] = o / fmaxf(den, 1e-6f);
    }
}

// ---------------------------------------------------------------------------
extern "C" void kernel_launch(void* const* d_in, const int* in_sizes, int n_in,
                              void* d_out, int out_size, void* d_ws, size_t ws_size,
                              hipStream_t stream) {
    const float* hin = (const float*)d_in[0];
    const float* e   = (const float*)d_in[1];
    const float* krw = (const float*)d_in[2];
    const float* Wq  = (const float*)d_in[3];
    const float* bq  = (const float*)d_in[4];
    const float* Wk  = (const float*)d_in[5];
    const float* bk  = (const float*)d_in[6];
    const float* We  = (const float*)d_in[7];
    const float* be  = (const float*)d_in[8];
    const float* Wv  = (const float*)d_in[9];
    const float* bv  = (const float*)d_in[10];
    float* out = (float*)d_out;

    char* ws = (char*)d_ws;
    unsigned short* WT  = (unsigned short*)ws;                   // 2 MB (slices 1..3)
    float* Q  = (float*)(ws + (2ull << 20));                     // 2 MB
    float* K  = (float*)(ws + (4ull << 20));                     // 2 MB
    float* V  = (float*)(ws + (6ull << 20));                     // 2 MB
    unsigned short* WT3 = (unsigned short*)(ws + (8ull << 20));  // 512 KB
    unsigned short* K2  = (unsigned short*)(ws + (9ull << 20));  // 1 MB

    k_wt  <<<dim3(8, 8, 3), dim3(256), 0, stream>>>(Wq, Wk, Wv, WT);
    k_wt3 <<<dim3(8, 8),    dim3(256), 0, stream>>>(We, WT3);
    k_qkv <<<dim3(16, 8, 3), dim3(256), 0, stream>>>(hin, WT, bq, bk, bv, Q, K, V);
    k_k2  <<<dim3(8, 8),    dim3(256), 0, stream>>>(K, K2);
    k_main<<<dim3(1024), dim3(1024), 0, stream>>>(e, krw, WT3, K2, be, Q, V, out);
}

// Round 10
// 220.332 us; speedup vs baseline: 6.9406x; 6.9406x over previous
//
#include <hip/hip_runtime.h>
#include <hip/hip_bf16.h>

// Problem constants
#define BB    8
#define NNODE 128
#define CIN   512
#define HH    8
#define DDIM  64
#define HD    512   // H*D

typedef float f32x4 __attribute__((ext_vector_type(4)));
typedef short bf16x8 __attribute__((ext_vector_type(8)));
typedef unsigned int u32x4 __attribute__((ext_vector_type(4)));

#define AS1 __attribute__((address_space(1)))
#define AS3 __attribute__((address_space(3)))

static __device__ __forceinline__ unsigned short f2bf(float f) {
    unsigned int x = __float_as_uint(f);
    x = x + 0x7FFFu + ((x >> 16) & 1u);
    return (unsigned short)(x >> 16);
}

static __device__ __forceinline__ bf16x8 pack8(f32x4 a, f32x4 b) {
    bf16x8 r;
    r[0] = (short)f2bf(a[0]); r[1] = (short)f2bf(a[1]);
    r[2] = (short)f2bf(a[2]); r[3] = (short)f2bf(a[3]);
    r[4] = (short)f2bf(b[0]); r[5] = (short)f2bf(b[1]);
    r[6] = (short)f2bf(b[2]); r[7] = (short)f2bf(b[3]);
    return r;
}

// fast f32x4 pair -> bf16x8 via v_cvt_pk_bf16_f32 (RNE)
static __device__ __forceinline__ bf16x8 cvt8(f32x4 a, f32x4 b) {
    union { u32x4 u; bf16x8 h8; } cv;
    asm("v_cvt_pk_bf16_f32 %0, %1, %2" : "=v"(cv.u[0]) : "v"(a[0]), "v"(a[1]));
    asm("v_cvt_pk_bf16_f32 %0, %1, %2" : "=v"(cv.u[1]) : "v"(a[2]), "v"(a[3]));
    asm("v_cvt_pk_bf16_f32 %0, %1, %2" : "=v"(cv.u[2]) : "v"(b[0]), "v"(b[1]));
    asm("v_cvt_pk_bf16_f32 %0, %1, %2" : "=v"(cv.u[3]) : "v"(b[2]), "v"(b[3]));
    return cv.h8;
}

// ---------------------------------------------------------------------------
// Kernel 1: tiled transpose+convert Wq/Wk/Wv [c][hd] f32 -> WT [m][hd][c] bf16
// ---------------------------------------------------------------------------
__global__ __launch_bounds__(256) void k_wt(
    const float* __restrict__ Wq, const float* __restrict__ Wk,
    const float* __restrict__ Wv,
    unsigned short* __restrict__ WT)
{
    __shared__ unsigned short tile[64][72];
    const int cb = blockIdx.x;
    const int hb = blockIdx.y;
    const int m  = blockIdx.z;          // 0=Wq,1=Wk,2=Wv
    const float* W = (m == 0) ? Wq : (m == 1) ? Wk : Wv;
    const int t = threadIdx.x;

#pragma unroll
    for (int it = 0; it < 4; ++it) {
        int row = it * 16 + (t >> 4);
        int col = (t & 15) * 4;
        f32x4 v = *reinterpret_cast<const f32x4*>(W + (size_t)(cb * 64 + row) * HD + hb * 64 + col);
        tile[row][col + 0] = f2bf(v[0]);
        tile[row][col + 1] = f2bf(v[1]);
        tile[row][col + 2] = f2bf(v[2]);
        tile[row][col + 3] = f2bf(v[3]);
    }
    __syncthreads();

#pragma unroll
    for (int it = 0; it < 4; ++it) {
        int hd = it * 16 + (t >> 4);
        int c  = (t & 15) * 4;
        unsigned long long pk =
            (unsigned long long)(unsigned short)tile[c + 0][hd] |
            ((unsigned long long)(unsigned short)tile[c + 1][hd] << 16) |
            ((unsigned long long)(unsigned short)tile[c + 2][hd] << 32) |
            ((unsigned long long)(unsigned short)tile[c + 3][hd] << 48);
        *reinterpret_cast<unsigned long long*>(
            &WT[((size_t)(m + 1) * HD + hb * 64 + hd) * CIN + cb * 64 + c]) = pk;
    }
}

// ---------------------------------------------------------------------------
// Kernel 2: QKV projections via bf16 MFMA (unchanged).
// ---------------------------------------------------------------------------
__global__ __launch_bounds__(256) void k_qkv(
    const float* __restrict__ hin,
    const unsigned short* __restrict__ WT,
    const float* __restrict__ bq, const float* __restrict__ bk, const float* __restrict__ bv,
    float* __restrict__ Qo, float* __restrict__ Ko, float* __restrict__ Vo)
{
    __shared__ unsigned short hs[64][520];
    const int rt = blockIdx.x;
    const int ct = blockIdx.y;
    const int m  = blockIdx.z;
    const int t  = threadIdx.x;
    const int w  = t >> 6;
    const int l  = t & 63;
    const int g  = l >> 4;
    const int c15 = l & 15;
    const float* bias = (m == 0) ? bq : (m == 1) ? bk : bv;
    float* Out = (m == 0) ? Qo : (m == 1) ? Ko : Vo;
    const unsigned short* Wm = WT + (size_t)(m + 1) * HD * CIN;
    const int rowbase = rt * 64;
    const int colbase = ct * 64;

#pragma unroll
    for (int q = 0; q < 32; ++q) {
        int f = q * 1024 + t * 4;
        int row = f >> 9;
        int c = f & 511;
        f32x4 hv = *reinterpret_cast<const f32x4*>(hin + (size_t)(rowbase + row) * CIN + c);
        unsigned long long pk =
            (unsigned long long)f2bf(hv[0]) |
            ((unsigned long long)f2bf(hv[1]) << 16) |
            ((unsigned long long)f2bf(hv[2]) << 32) |
            ((unsigned long long)f2bf(hv[3]) << 48);
        *reinterpret_cast<unsigned long long*>(&hs[row][c]) = pk;
    }
    __syncthreads();

    f32x4 acc[4];
#pragma unroll
    for (int nf = 0; nf < 4; ++nf) acc[nf] = (f32x4){0.f, 0.f, 0.f, 0.f};

#pragma unroll
    for (int kt = 0; kt < 16; ++kt) {
        bf16x8 afr = *reinterpret_cast<const bf16x8*>(&hs[w * 16 + c15][kt * 32 + g * 8]);
#pragma unroll
        for (int nf = 0; nf < 4; ++nf) {
            const unsigned short* wp = Wm + (size_t)(colbase + nf * 16 + c15) * CIN + kt * 32 + g * 8;
            bf16x8 bfr = *reinterpret_cast<const bf16x8*>(wp);
            acc[nf] = __builtin_amdgcn_mfma_f32_16x16x32_bf16(afr, bfr, acc[nf], 0, 0, 0);
        }
    }

    const float scale = (m == 1) ? 0.125f : 1.0f;
#pragma unroll
    for (int nf = 0; nf < 4; ++nf) {
        int col = colbase + nf * 16 + c15;
        float bv_ = bias[col];
#pragma unroll
        for (int r = 0; r < 4; ++r) {
            int row = rowbase + w * 16 + g * 4 + r;
            Out[(size_t)row * HD + col] = (acc[nf][r] + bv_) * scale;
        }
    }
}

// ---------------------------------------------------------------------------
// Kernel 1b: We -> WTB, B-fragment-linear for 16x16x32 (K = c, N = hd).
// WTB[((h*8+ct)*8 + kt*4+nf)*512 + l*8 + i]
//   = bf16(We[ct*64 + kt*32 + (l>>4)*8 + i][h*64 + nf*16 + (l&15)])
// ---------------------------------------------------------------------------
__global__ __launch_bounds__(256) void k_wtb(
    const float* __restrict__ We, unsigned short* __restrict__ WTB)
{
    const int h  = blockIdx.x;          // 0..7
    const int ct = blockIdx.y;          // 0..7
    const int t  = threadIdx.x;
#pragma unroll
    for (int it = 0; it < 2; ++it) {
        int s  = it * 256 + t;          // (kt,nf,l): 2*4*64 = 512
        int kt = s >> 8, nf = (s >> 6) & 3, l = s & 63;
        int c0 = ct * 64 + kt * 32 + (l >> 4) * 8;
        int hd = h * 64 + nf * 16 + (l & 15);
        bf16x8 v;
#pragma unroll
        for (int i = 0; i < 8; ++i)
            v[i] = (short)f2bf(We[(size_t)(c0 + i) * HD + hd]);
        size_t off = ((size_t)(h * 8 + ct) * 8 + kt * 4 + nf) * 512 + l * 8;
        *reinterpret_cast<bf16x8*>(&WTB[off]) = v;
    }
}

// ---------------------------------------------------------------------------
// Kernel 3 v10: direct GEMM E2 = e@We per block (b,i); 512 thr = 8 waves = heads.
// A = e (f32 in LDS via global_load_lds, cvt to bf16 at fragment load);
// B = We frags (WTB, coalesced 1KB loads, double-buffered regs, FIFO-ordered);
// acc[8][4] in AGPRs (proven no-spill shape). 8 phases of 64 c, 3 LDS bufs,
// counted vmcnt(4) keeps newest e-tile in flight across each barrier.
// Epilogue: scores = sum_d (E2+be)*Q*K -> exp/clip * k_RW -> PV + out.
// ---------------------------------------------------------------------------
__global__ __launch_bounds__(512, 1) void k_main(
    const float* __restrict__ e, const float* __restrict__ k_RW,
    const unsigned short* __restrict__ WTB, const float* __restrict__ be,
    const float* __restrict__ Qw, const float* __restrict__ Kw,
    const float* __restrict__ Vw, float* __restrict__ out)
{
    __shared__ float e_s[3 * 8192];     // 3 x 32 KB tiles [j 0..127][swizzled c 0..63]
    __shared__ float s_lds[8][128];

    const int bx = blockIdx.x;
    const int bi = (bx & 7) * 128 + (bx >> 3);   // XCD swizzle (1024 % 8 == 0)
    const int b  = bi >> 7;
    const int t  = threadIdx.x;
    const int h  = t >> 6;              // wave id == head
    const int l  = t & 63;
    const int g  = l >> 4;
    const int c15 = l & 15;

    const float* ebase = e + (size_t)bi * NNODE * CIN;

    // epilogue operands first (oldest FIFO entries; drained by first entry wait)
    float q_l[4], be_l[4];
#pragma unroll
    for (int nf = 0; nf < 4; ++nf) {
        q_l[nf]  = Qw[(size_t)bi * HD + h * 64 + nf * 16 + c15];
        be_l[nf] = be[h * 64 + nf * 16 + c15];
    }

    f32x4 acc[8][4];
#pragma unroll
    for (int mf = 0; mf < 8; ++mf)
#pragma unroll
        for (int nf = 0; nf < 4; ++nf)
            acc[mf][nf] = (f32x4){0.f, 0.f, 0.f, 0.f};

    // per-lane LDS read sub-offsets: slot = (kt*8 + g*2 + p) ^ c15  (16B granules)
    const int s00 = (((g * 2) + 0) ^ c15) << 4;
    const int s01 = (((g * 2) + 1) ^ c15) << 4;
    const int s10 = ((8 + (g * 2) + 0) ^ c15) << 4;
    const int s11 = ((8 + (g * 2) + 1) ^ c15) << 4;

    // STAGE(TT): wave h stages rows [h*16, h*16+16) of e-tile TT (64 c f32).
    // instr q: rows h*16+q*4+g; dest linear (wave base + lane*16B);
    // source granule pre-swizzled by key = row&15 = q*4+g (rule #21).
#define STAGE(TT) do {                                                          \
        _Pragma("unroll")                                                       \
        for (int q_ = 0; q_ < 4; ++q_) {                                        \
            const int key_ = q_ * 4 + g;                                        \
            const float* src_ = ebase + (size_t)(h * 16 + key_) * CIN           \
                                + (TT) * 64 + ((c15 ^ key_) << 2);              \
            __builtin_amdgcn_global_load_lds(                                   \
                (const AS1 unsigned int*)src_,                                  \
                (AS3 unsigned int*)((char*)&e_s[0] + ((TT) % 3) * 32768         \
                                    + h * 4096 + q_ * 1024), 16, 0, 0);         \
        }                                                                       \
    } while (0)

#define LOADB(CT, B) do {                                                       \
        const unsigned short* bp_ = WTB + ((size_t)(h * 8 + (CT)) * 8) * 512 + l * 8; \
        _Pragma("unroll")                                                       \
        for (int f_ = 0; f_ < 8; ++f_)                                          \
            B[f_] = *reinterpret_cast<const bf16x8*>(bp_ + f_ * 512);           \
    } while (0)

#define COMPUTE(CT, BC) do {                                                    \
        const char* ebuf_ = (const char*)&e_s[0] + ((CT) % 3) * 32768;          \
        _Pragma("unroll")                                                       \
        for (int mf_ = 0; mf_ < 8; ++mf_) {                                     \
            const char* rp_ = ebuf_ + (mf_ * 16 + c15) * 256;                   \
            bf16x8 a0_ = cvt8(*(const f32x4*)(rp_ + s00),                       \
                              *(const f32x4*)(rp_ + s01));                      \
            bf16x8 a1_ = cvt8(*(const f32x4*)(rp_ + s10),                       \
                              *(const f32x4*)(rp_ + s11));                      \
            _Pragma("unroll")                                                   \
            for (int nf_ = 0; nf_ < 4; ++nf_) {                                 \
                acc[mf_][nf_] = __builtin_amdgcn_mfma_f32_16x16x32_bf16(        \
                    a0_, BC[nf_], acc[mf_][nf_], 0, 0, 0);                      \
                acc[mf_][nf_] = __builtin_amdgcn_mfma_f32_16x16x32_bf16(        \
                    a1_, BC[4 + nf_], acc[mf_][nf_], 0, 0, 0);                  \
            }                                                                   \
        }                                                                       \
    } while (0)

#define PHASE(CT, BC, BN) do {                                                  \
        if ((CT) < 7) { asm volatile("s_waitcnt vmcnt(4)" ::: "memory"); }      \
        else          { asm volatile("s_waitcnt vmcnt(0)" ::: "memory"); }      \
        __builtin_amdgcn_sched_barrier(0);                                      \
        __builtin_amdgcn_s_barrier();                                           \
        __builtin_amdgcn_sched_barrier(0);                                      \
        if ((CT) < 7) { LOADB((CT) + 1, BN); }                                  \
        __builtin_amdgcn_sched_barrier(0);                                      \
        if ((CT) < 6) { STAGE((CT) + 2); }                                      \
        __builtin_amdgcn_sched_barrier(0);                                      \
        COMPUTE(CT, BC);                                                        \
    } while (0)

    bf16x8 B0[8], B1[8];

    // prologue FIFO: [Q/be:8, S(0):4, B(0):8, S(1):4]
    STAGE(0);
    LOADB(0, B0);
    STAGE(1);
    __builtin_amdgcn_sched_barrier(0);

    PHASE(0, B0, B1);
    PHASE(1, B1, B0);
    PHASE(2, B0, B1);
    PHASE(3, B1, B0);
    PHASE(4, B0, B1);
    PHASE(5, B1, B0);
    PHASE(6, B0, B1);
    PHASE(7, B1, B0);
#undef PHASE
#undef COMPUTE
#undef LOADB
#undef STAGE

    // ---- epilogue: scores s[j] = sum_d (E2[j,d]+be[d])*Q[d]*K[j,d] ----
    const float* Kb  = Kw + (size_t)b * NNODE * HD;
    const float* krw = k_RW + (size_t)bi * NNODE;
#pragma unroll
    for (int mf = 0; mf < 8; ++mf) {
#pragma unroll
        for (int r = 0; r < 4; ++r) {
            int j = mf * 16 + g * 4 + r;
            float s = 0.f;
#pragma unroll
            for (int nf = 0; nf < 4; ++nf) {
                float kv = Kb[(size_t)j * HD + h * 64 + nf * 16 + c15];
                s += (acc[mf][nf][r] + be_l[nf]) * q_l[nf] * kv;
            }
            s += __shfl_xor(s, 1);
            s += __shfl_xor(s, 2);
            s += __shfl_xor(s, 4);
            s += __shfl_xor(s, 8);
            if (c15 == 0)
                s_lds[h][j] = __expf(fminf(fmaxf(s, -5.f), 5.f)) * krw[j];
        }
    }

    // ---- PV + denom (wave-private row of s_lds; same-wave visibility) ----
    const float* Vb = Vw + (size_t)b * NNODE * HD + h * 64 + l;
    float o = 0.f, den = 0.f;
#pragma unroll 4
    for (int jl = 0; jl < NNODE; ++jl) {
        float sv = s_lds[h][jl];
        o = fmaf(sv, Vb[(size_t)jl * HD], o);
        den += sv;
    }
    out[(size_t)bi * HD + h * 64 + l] = o / fmaxf(den, 1e-6f);
}

// ---------------------------------------------------------------------------
extern "C" void kernel_launch(void* const* d_in, const int* in_sizes, int n_in,
                              void* d_out, int out_size, void* d_ws, size_t ws_size,
                              hipStream_t stream) {
    const float* hin = (const float*)d_in[0];
    const float* e   = (const float*)d_in[1];
    const float* krw = (const float*)d_in[2];
    const float* Wq  = (const float*)d_in[3];
    const float* bq  = (const float*)d_in[4];
    const float* Wk  = (const float*)d_in[5];
    const float* bk  = (const float*)d_in[6];
    const float* We  = (const float*)d_in[7];
    const float* be  = (const float*)d_in[8];
    const float* Wv  = (const float*)d_in[9];
    const float* bv  = (const float*)d_in[10];
    float* out = (float*)d_out;

    char* ws = (char*)d_ws;
    unsigned short* WT  = (unsigned short*)ws;                   // 2 MB (slices 1..3)
    float* Q  = (float*)(ws + (2ull << 20));                     // 2 MB
    float* K  = (float*)(ws + (4ull << 20));                     // 2 MB
    float* V  = (float*)(ws + (6ull << 20));                     // 2 MB
    unsigned short* WTB = (unsigned short*)(ws + (8ull << 20));  // 512 KB

    k_wt  <<<dim3(8, 8, 3), dim3(256), 0, stream>>>(Wq, Wk, Wv, WT);
    k_wtb <<<dim3(8, 8),    dim3(256), 0, stream>>>(We, WTB);
    k_qkv <<<dim3(16, 8, 3), dim3(256), 0, stream>>>(hin, WT, bq, bk, bv, Q, K, V);
    k_main<<<dim3(1024), dim3(512), 0, stream>>>(e, krw, WTB, be, Q, K, V, out);
}